// Round 11
// baseline (887.256 us; speedup 1.0000x reference)
//
#include <hip/hip_runtime.h>
#include <hip/hip_bf16.h>
#include <math.h>

#define NN 16384
#define IN_DIM 256
#define HID 128
#define MAXL 128
#define NCLS 64
#define EPS 1e-5f
#define SROW 144  // u16 per S row: 16 data chunks + 2 pad; 72 dw = 8 mod 32

typedef unsigned short u16;
typedef unsigned int u32;
typedef __attribute__((ext_vector_type(8))) short short8;
typedef __attribute__((ext_vector_type(4))) float f32x4;

// scr layout (floats), ALIASED onto S (only used after last read of S data):
// POOLED[128] | RSC[256..]. All scr/csum use is write-before-read flat f32,
// so no pre-zeroing of pads is needed anywhere.
#define POOLED 0
#define RSC 128
#define Z1 384

__device__ __forceinline__ u16 f2bf(float f) {
  union { float f; u32 i; } v; v.f = f;
  u32 x = v.i;
  u32 r = (x + 0x7fffu + ((x >> 16) & 1u)) >> 16;
  return (u16)r;
}
#if __has_builtin(__builtin_amdgcn_cvt_pk_bf16_f32)
typedef __bf16 bf16x2 __attribute__((ext_vector_type(2)));
__device__ __forceinline__ u32 pack2(float a, float b) {
  bf16x2 h = __builtin_amdgcn_cvt_pk_bf16_f32(a, b);
  u32 u;
  __builtin_memcpy(&u, &h, 4);
  return u;
}
#else
__device__ __forceinline__ u32 pack2(float a, float b) {
  return (u32)f2bf(a) | ((u32)f2bf(b) << 16);
}
#endif

__device__ __forceinline__ float fast_exp2(float x) {
#if __has_builtin(__builtin_amdgcn_exp2f)
  return __builtin_amdgcn_exp2f(x);
#else
  return exp2f(x);
#endif
}
__device__ __forceinline__ float fast_rcp(float x) {
#if __has_builtin(__builtin_amdgcn_rcpf)
  return __builtin_amdgcn_rcpf(x);
#else
  return 1.0f / x;
#endif
}
// tanh-form GELU: x * (1 - 1/(1+exp2(x*(A + B*x^2))))
__device__ __forceinline__ float gelu_fast(float x) {
  float s = x * x;
  float p = __builtin_fmaf(s, 0.1029445f, 2.3022038f);
  float e = fast_exp2(x * p);
  float r = fast_rcp(e + 1.0f);
  return x - x * r;
}

// ---- 16-lane (DPP row) butterfly reduction on the VALU pipe
template <int CTRL>
__device__ __forceinline__ float dpp_add(float x) {
  int y = __builtin_amdgcn_update_dpp(0, __builtin_bit_cast(int, x), CTRL,
                                      0xF, 0xF, true);
  return x + __builtin_bit_cast(float, y);
}
__device__ __forceinline__ float row_reduce16(float x) {
  x = dpp_add<0xB1>(x);   // quad_perm [1,0,3,2]  (xor 1)
  x = dpp_add<0x4E>(x);   // quad_perm [2,3,0,1]  (xor 2)
  x = dpp_add<0x124>(x);  // row_ror:4  (cross-quad)
  x = dpp_add<0x128>(x);  // row_ror:8  (cross-half)
  return x;
}

// ---------------- K1: H = LN(GELU(node_feat @ local_W + b)), 8 nodes/block --
__global__ __launch_bounds__(128) void k_local_encoder(
    const float* __restrict__ node_feat, const float* __restrict__ local_W,
    const float* __restrict__ local_b, const float* __restrict__ lnw,
    const float* __restrict__ lnb, u16* __restrict__ H) {
  __shared__ float x[8][IN_DIM];
  __shared__ float red[8][2][2];
  int n0 = blockIdx.x * 8, j = threadIdx.x;
  for (int q = j; q < 8 * IN_DIM; q += 128)
    x[q >> 8][q & 255] = node_feat[n0 * IN_DIM + q];
  __syncthreads();
  float acc[8];
#pragma unroll
  for (int p = 0; p < 8; ++p) acc[p] = local_b[j];
  for (int k = 0; k < IN_DIM; ++k) {
    float w = local_W[k * HID + j];
#pragma unroll
    for (int p = 0; p < 8; ++p) acc[p] += x[p][k] * w;
  }
  float lw = lnw[j], lb = lnb[j];
  int wave = j >> 6;
  float g[8];
#pragma unroll
  for (int p = 0; p < 8; ++p) {
    g[p] = gelu_fast(acc[p]);
    float s = g[p], ss = g[p] * g[p];
#pragma unroll
    for (int o = 1; o < 64; o <<= 1) {
      s += __shfl_xor(s, o, 64);
      ss += __shfl_xor(ss, o, 64);
    }
    if ((j & 63) == 0) { red[p][wave][0] = s; red[p][wave][1] = ss; }
  }
  __syncthreads();
#pragma unroll
  for (int p = 0; p < 8; ++p) {
    float S = red[p][0][0] + red[p][1][0];
    float SS = red[p][0][1] + red[p][1][1];
    float m = S * (1.0f / 128.0f);
    float v = SS * (1.0f / 128.0f) - m * m;
    float y = (g[p] - m) * rsqrtf(v + EPS) * lw + lb;
    H[(n0 + p) * HID + j] = f2bf(y);
  }
}

// ------- K2: repack weights to bf16, A-fragment (wave-coalesced) order -----
// layout in dst: conv [0, CONV_ELEMS) | ssm [.., +HID*HID) | biasrow [.., +HID)
#define CONV_ELEMS (3 * 4 * 3 * 8 * 512)  // 147456
#define PREP_TOTAL (CONV_ELEMS + HID * HID + HID)
__global__ __launch_bounds__(256) void k_prep(
    const float* __restrict__ conv_w, const float* __restrict__ ssm_W,
    const float* __restrict__ ssm_b, u16* __restrict__ dst) {
  int idx = blockIdx.x * 256 + threadIdx.x;
  if (idx >= PREP_TOTAL) return;
  if (idx < CONV_ELEMS) {
    int e = idx & 7, quad = (idx >> 3) & 3, li16 = (idx >> 5) & 15,
        g = (idx >> 9) & 7;
    int rest = idx >> 12;  // 0..35 = ((li*4+kc)*3+tap)
    int tap = rest % 3, kcli = rest / 3;
    int kc = kcli & 3, li = kcli >> 2;
    int co = g * 16 + li16, ci = kc * 32 + quad * 8 + e;
    dst[idx] = f2bf(conv_w[((li * HID + co) * HID + ci) * 3 + tap]);
  } else if (idx < CONV_ELEMS + HID * HID) {
    int r = idx - CONV_ELEMS;
    int e = r & 7, quad = (r >> 3) & 3, li16 = (r >> 5) & 15, g = (r >> 9) & 7;
    int kc = r >> 12;
    dst[idx] = f2bf(ssm_W[(kc * 32 + quad * 8 + e) * HID + g * 16 + li16]);
  } else {
    // bf16 ssm bias row: the exact value padded sequence rows take
    dst[idx] = f2bf(ssm_b[idx - CONV_ELEMS - HID * HID]);
  }
}

// ---------------- GEMM core: D[co][l] = sum_ci,tap W[co][ci] * Sin[l+shift][ci]
// w_frag (A): lane m=li16 -> co, k = quad*8+e  -> coalesced 1KB global chunk
// x_frag (B): lane n=li16 -> l,  k = quad*8+e  -> ds_read_b128 of Sin row
// chunk swizzle: phys = c ^ (row & 7); 16j = 0 mod 8 -> j-invariant
// b fragments loaded in groups of 2 (not 4): caps the GEMM-peak register
// demand so the whole kernel fits 128 unified regs (4 waves/SIMD).
template <int TAPS, int DIL>
__device__ __forceinline__ void run_gemm(f32x4 (*acc)[8],
                                         const u16* __restrict__ Wg,
                                         const u16* __restrict__ Sin, int li16,
                                         int quad, int w) {
  const u16* wbase = Wg + w * 1024 + li16 * 32 + quad * 8;
#pragma unroll
  for (int kc = 0; kc < 4; ++kc) {
#pragma unroll
    for (int tap = 0; tap < TAPS; ++tap) {
      const int shift = (TAPS == 3) ? (tap - 1) * DIL : 0;
      const u16* wp = wbase + (kc * TAPS + tap) * 4096;
      short8 a0 = *(const short8*)wp;
      short8 a1 = *(const short8*)(wp + 512);
      int base_row = 4 + li16 + shift;
      int phys = (kc * 4 + quad) ^ (base_row & 7);
      const u16* sp = Sin + base_row * SROW + phys * 8;
#pragma unroll
      for (int j0 = 0; j0 < 8; j0 += 2) {
        short8 b[2];
#pragma unroll
        for (int jj = 0; jj < 2; ++jj)
          b[jj] = *(const short8*)(sp + (j0 + jj) * 16 * SROW);
#pragma unroll
        for (int jj = 0; jj < 2; ++jj) {
          acc[0][j0 + jj] = __builtin_amdgcn_mfma_f32_16x16x32_bf16(
              a0, b[jj], acc[0][j0 + jj], 0, 0, 0);
          acc[1][j0 + jj] = __builtin_amdgcn_mfma_f32_16x16x32_bf16(
              a1, b[jj], acc[1][j0 + jj], 0, 0, 0);
        }
      }
    }
  }
}

// init accumulators with per-co bias (uniform over l)
__device__ __forceinline__ void bias_acc(f32x4 (*acc)[8],
                                         const float* __restrict__ cb,
                                         int cobase, int quad) {
#pragma unroll
  for (int i = 0; i < 2; ++i) {
    f32x4 b4 = *(const f32x4*)(cb + cobase + i * 16 + quad * 4);
#pragma unroll
    for (int j = 0; j < 8; ++j) acc[i][j] = b4;
  }
}

// ------------- K_SSM: H2 = H @ ssm_W + ssm_b (once per node, in place) -----
// 128 nodes/block; stages H rows into the same swizzled S layout, one
// run_gemm<1,0>, bf16-pack, store back over H. Bit-identical to the former
// per-gather ssm stage (same mfma order, same f32 bias add, same pack).
__global__ __launch_bounds__(256) void k_ssm(const float* __restrict__ ssm_b,
                                             const u16* __restrict__ ssmW3,
                                             u16* __restrict__ H) {
  __shared__ __align__(16) u16 S[136 * SROW];
  int t = threadIdx.x;
  int lane = t & 63, w = t >> 6;
  int li16 = lane & 15, quad = lane >> 4;
  int n0 = blockIdx.x * 128;
  {
    int l = t >> 1, h = t & 1;
    const uint4* Hrow = (const uint4*)(H + (n0 + l) * HID + h * 64);
    int row = 4 + l, rx = row & 7;
#pragma unroll
    for (int mb = 0; mb < 8; ++mb) {
      uint4 v = Hrow[mb];
      int phys = (h * 8 + mb) ^ rx;
      *(uint4*)&S[row * SROW + phys * 8] = v;
    }
  }
  __syncthreads();  // all H reads staged before in-place overwrite
  f32x4 acc[2][8];
  int cobase = w * 32;
  bias_acc(acc, ssm_b, cobase, quad);
  run_gemm<1, 0>(acc, ssmW3, S, li16, quad, w);
  u32* H2 = (u32*)H;
#pragma unroll
  for (int i = 0; i < 2; ++i) {
    int co0 = cobase + i * 16 + quad * 4;
#pragma unroll
    for (int j = 0; j < 8; ++j) {
      int node = n0 + 16 * j + li16;
      uint2 pk;
      pk.x = pack2(acc[i][j][0], acc[i][j][1]);
      pk.y = pack2(acc[i][j][2], acc[i][j][3]);
      *(uint2*)&H2[node * 64 + co0 / 2] = pk;  // 8B-aligned (co0 % 4 == 0)
    }
  }
}

// conv stage IN PLACE on S, WRITE-THROUGH epilogue: gemm -> barrier (all
// reads done) -> gelu/LN and store each packed uint2 AS COMPUTED -> barrier.
// No pk[2][8] register array is ever live: epilogue peak = acc + stats only,
// which is what lets the kernel fit the 128-reg / 4-waves-per-SIMD tier.
template <int DIL>
__device__ __forceinline__ void conv_stage(
    f32x4 (*acc)[8], const u16* __restrict__ Wg, u16* __restrict__ S,
    int li16, int quad, int w, const float* __restrict__ cb,
    const float* __restrict__ gw, const float* __restrict__ gb) {
  int cobase = w * 32;
  bias_acc(acc, cb, cobase, quad);
  run_gemm<3, DIL>(acc, Wg, S, li16, quad, w);
  __syncthreads();  // all waves' reads of S complete; writes may now proceed
#pragma unroll
  for (int i = 0; i < 2; ++i) {
    f32x4 s = (f32x4){0.f, 0.f, 0.f, 0.f}, ss = s;
#pragma unroll
    for (int j = 0; j < 8; ++j) {
#pragma unroll
      for (int r = 0; r < 4; ++r) acc[i][j][r] = gelu_fast(acc[i][j][r]);
      s += acc[i][j];
      ss += acc[i][j] * acc[i][j];
    }
    // reduce over the 16 l-lanes (DPP row ops, VALU pipe — no LDS)
#pragma unroll
    for (int r = 0; r < 4; ++r) {
      s[r] = row_reduce16(s[r]);
      ss[r] = row_reduce16(ss[r]);
    }
    f32x4 inv, im;
#pragma unroll
    for (int r = 0; r < 4; ++r) {
      float m = s[r] * (1.0f / 128.0f);
      float var = ss[r] * (1.0f / 128.0f) - m * m;
      inv[r] = rsqrtf(var + EPS);
      im[r] = m * inv[r];
    }
    int c8 = w * 4 + 2 * i + (quad >> 1);
    // y = fma(fma(acc, inv, -im), gl, bl); packed+stored immediately
#pragma unroll
    for (int j = 0; j < 8; ++j) {
      int l = 16 * j + li16;
      float gl = gw[l], bl = gb[l];  // streamed from L1, not reg-resident
      float y0 = __builtin_fmaf(__builtin_fmaf(acc[i][j][0], inv[0], -im[0]), gl, bl);
      float y1 = __builtin_fmaf(__builtin_fmaf(acc[i][j][1], inv[1], -im[1]), gl, bl);
      float y2 = __builtin_fmaf(__builtin_fmaf(acc[i][j][2], inv[2], -im[2]), gl, bl);
      float y3 = __builtin_fmaf(__builtin_fmaf(acc[i][j][3], inv[3], -im[3]), gl, bl);
      uint2 pk;
      pk.x = pack2(y0, y1);
      pk.y = pack2(y2, y3);
      int row = 4 + 16 * j + li16;
      int phys = c8 ^ (row & 7);
      *(uint2*)&S[row * SROW + phys * 8 + (quad & 1) * 4] = pk;
    }
  }
  __syncthreads();  // S writes visible before next stage reads
}

// FINAL conv stage with FUSED masked pooling: conv3's output is only pooled,
// so never pack/store it. Masked LN coefficients (0 for padded l) make y
// exactly 0 for invalid positions via fma(q,0,0); pool-sum runs in registers
// + DPP row-reduce; each csum[co] has exactly ONE writer (li16==0 lane) ->
// plain f32x4 stores, no atomics, no pre-zeroing. csum aliases guard rows
// the GEMM reads as halo, so its write must wait for the reads-done barrier.
template <int DIL>
__device__ __forceinline__ void conv_stage_pool(
    f32x4 (*acc)[8], const u16* __restrict__ Wg, u16* __restrict__ S,
    int li16, int quad, int w, const float* __restrict__ cb,
    const float* __restrict__ gw, const float* __restrict__ gb, int len,
    float* __restrict__ csum) {
  int cobase = w * 32;
  bias_acc(acc, cb, cobase, quad);
  run_gemm<3, DIL>(acc, Wg, S, li16, quad, w);
  f32x4 ps[2];
#pragma unroll
  for (int i = 0; i < 2; ++i) {
    f32x4 s = (f32x4){0.f, 0.f, 0.f, 0.f}, ss = s;
#pragma unroll
    for (int j = 0; j < 8; ++j) {
#pragma unroll
      for (int r = 0; r < 4; ++r) acc[i][j][r] = gelu_fast(acc[i][j][r]);
      s += acc[i][j];
      ss += acc[i][j] * acc[i][j];
    }
    // LN stats over ALL 128 l (reference semantics: LN ignores the mask)
#pragma unroll
    for (int r = 0; r < 4; ++r) {
      s[r] = row_reduce16(s[r]);
      ss[r] = row_reduce16(ss[r]);
    }
    f32x4 inv, im;
#pragma unroll
    for (int r = 0; r < 4; ++r) {
      float m = s[r] * (1.0f / 128.0f);
      float var = ss[r] * (1.0f / 128.0f) - m * m;
      inv[r] = rsqrtf(var + EPS);
      im[r] = m * inv[r];
    }
    ps[i] = (f32x4){0.f, 0.f, 0.f, 0.f};
#pragma unroll
    for (int j = 0; j < 8; ++j) {
      int l = 16 * j + li16;
      bool valid = l < len;
      float glm = valid ? gw[l] : 0.f;  // streamed + masked
      float blm = valid ? gb[l] : 0.f;
#pragma unroll
      for (int r = 0; r < 4; ++r)
        ps[i][r] += __builtin_fmaf(
            __builtin_fmaf(acc[i][j][r], inv[r], -im[r]), glm, blm);
    }
#pragma unroll
    for (int r = 0; r < 4; ++r) ps[i][r] = row_reduce16(ps[i][r]);
  }
  __syncthreads();  // all waves' gemm reads of S (incl. guard rows) complete
  if (li16 == 0) {
#pragma unroll
    for (int i = 0; i < 2; ++i)
      *(f32x4*)&csum[cobase + 16 * i + quad * 4] = ps[i];
  }
  __syncthreads();  // csum visible for the matvec
}

__global__ __launch_bounds__(256, 4) void k_main(
    const int* __restrict__ nidx, const int* __restrict__ nlen,
    const u16* __restrict__ Hg, const u16* __restrict__ biasrow,
    const u16* __restrict__ convW3, const float* __restrict__ conv_b,
    const float* __restrict__ lnw, const float* __restrict__ lnb,
    const float* __restrict__ out_W, const float* __restrict__ out_b,
    const float* __restrict__ W1, const float* __restrict__ b1,
    const float* __restrict__ W2, const float* __restrict__ b2,
    float* __restrict__ out) {
  // SINGLE buffer: 136*144*2 = 39168 B.  scr (classifier scratch) aliases S
  // data rows; csum lives in guard rows 132..133 and is written (not
  // accumulated) only after conv3's reads, so no zeroing/atomics needed.
  __shared__ __align__(16) u16 S[136 * SROW];
  float* scr = (float*)S;
  float* csum = (float*)&S[132 * SROW];  // 128 floats

  int n = blockIdx.x, t = threadIdx.x;
  int lane = t & 63, w = t >> 6;
  int li16 = lane & 15, quad = lane >> 4;
  int len = nlen[n];

  // zero guard rows: 16 data chunks per row (8 rows x 16 chunks = 128 uint4);
  // GEMMs read these as the zero-padding halo for the dilated convs
  if (t < 128) {
    int rg = t >> 4, c = t & 15;
    int row = (rg < 4) ? rg : 128 + rg;  // rows 0..3, 132..135
    uint4 z; z.x = 0; z.y = 0; z.z = 0; z.w = 0;
    *(uint4*)&S[row * SROW + c * 8] = z;
  }
  // gather: S row (4+l) = H2[nidx[l]] (ssm output, hoisted) or bias row
  {
    int l = t >> 1, h = t & 1;
    int nb = nidx[n * MAXL + l];
    bool valid = l < len;
    const uint4* src = valid ? (const uint4*)(Hg + nb * HID + h * 64)
                             : (const uint4*)(biasrow + h * 64);
    int row = 4 + l, rx = row & 7;
#pragma unroll
    for (int mb = 0; mb < 8; ++mb) {
      uint4 v = src[mb];
      int phys = (h * 8 + mb) ^ rx;
      *(uint4*)&S[row * SROW + phys * 8] = v;
    }
  }
  __syncthreads();

  f32x4 acc[2][8];

  // ---- 3 dilated conv layers in place on S; conv3 fuses the masked pool
  conv_stage<1>(acc, convW3, S, li16, quad, w, conv_b, lnw, lnb);
  conv_stage<2>(acc, convW3 + 49152, S, li16, quad, w, conv_b + HID,
                lnw + HID, lnb + HID);
  conv_stage_pool<4>(acc, convW3 + 98304, S, li16, quad, w, conv_b + 2 * HID,
                     lnw + 2 * HID, lnb + 2 * HID, len, csum);

  // ---- project pooled sum: pooled = (csum @ out_W)/len + out_b
  // (identical algebra to pooling after projection; f32 order differs only)
  {
    int co = t & 127, part = t >> 7;
    const float* wcol = out_W + co;
    float a = 0.f;
    int ci0 = part * 64;
#pragma unroll 8
    for (int ci = ci0; ci < ci0 + 64; ++ci)
      a = __builtin_fmaf(csum[ci], wcol[ci * HID], a);
    scr[RSC + part * 128 + co] = a;
  }
  __syncthreads();
  if (t < 128) {
    float denom = (len > 0) ? (float)len : 1.0f;
    float p = (scr[RSC + t] + scr[RSC + 128 + t]) / denom;
    scr[POOLED + t] = (len > 0) ? (p + out_b[t]) : 0.f;
  }
  __syncthreads();
  // ---- classifier (4 partials; partial layout part*64+j is conflict-free)
  {
    int part = t >> 6, j = t & 63;
    float s = 0.f;
    int c0 = part * 32;
#pragma unroll 8
    for (int c = c0; c < c0 + 32; ++c) s += scr[POOLED + c] * W1[c * 64 + j];
    scr[RSC + part * 64 + j] = s;
  }
  __syncthreads();
  if (t < 64) {
    float z = b1[t] + scr[RSC + t] + scr[RSC + 64 + t] + scr[RSC + 128 + t] +
              scr[RSC + 192 + t];
    scr[Z1 + t] = gelu_fast(z);
  }
  __syncthreads();
  {
    int part = t >> 6, j = t & 63;
    float s = 0.f;
    int c0 = part * 16;
#pragma unroll 8
    for (int c = c0; c < c0 + 16; ++c) s += scr[Z1 + c] * W2[c * 64 + j];
    scr[RSC + part * 64 + j] = s;
  }
  __syncthreads();
  if (t < 64) {
    out[n * NCLS + t] = b2[t] + scr[RSC + t] + scr[RSC + 64 + t] +
                        scr[RSC + 128 + t] + scr[RSC + 192 + t];
  }
}

extern "C" void kernel_launch(void* const* d_in, const int* in_sizes, int n_in,
                              void* d_out, int out_size, void* d_ws,
                              size_t ws_size, hipStream_t stream) {
  const float* node_feat = (const float*)d_in[0];
  const int* nidx = (const int*)d_in[1];
  const int* nlen = (const int*)d_in[2];
  const float* local_W = (const float*)d_in[3];
  const float* local_b = (const float*)d_in[4];
  const float* local_ln_w = (const float*)d_in[5];
  const float* local_ln_b = (const float*)d_in[6];
  const float* ssm_W = (const float*)d_in[7];
  const float* ssm_b = (const float*)d_in[8];
  const float* conv_w = (const float*)d_in[9];
  const float* conv_b = (const float*)d_in[10];
  const float* lnw = (const float*)d_in[11];
  const float* lnb = (const float*)d_in[12];
  const float* outW = (const float*)d_in[13];
  const float* outb = (const float*)d_in[14];
  const float* W1 = (const float*)d_in[15];
  const float* b1 = (const float*)d_in[16];
  const float* W2 = (const float*)d_in[17];
  const float* b2 = (const float*)d_in[18];

  u16* Hws = (u16*)d_ws;                // 16384*128 bf16 (H, then H2 in place)
  u16* convW3 = Hws + NN * HID;         // 147456
  u16* ssmW3 = convW3 + CONV_ELEMS;     // 16384
  u16* biasrow = ssmW3 + HID * HID;     // 128

  k_local_encoder<<<NN / 8, 128, 0, stream>>>(node_feat, local_W, local_b,
                                              local_ln_w, local_ln_b, Hws);
  k_prep<<<(PREP_TOTAL + 255) / 256, 256, 0, stream>>>(conv_w, ssm_W, ssm_b,
                                                       convW3);
  k_ssm<<<NN / 128, 256, 0, stream>>>(ssm_b, ssmW3, Hws);
  k_main<<<NN, 256, 0, stream>>>(nidx, nlen, Hws, biasrow, convW3, conv_b,
                                 lnw, lnb, outW, outb, W1, b1, W2, b2,
                                 (float*)d_out);
}

// Round 12
// 859.526 us; speedup vs baseline: 1.0323x; 1.0323x over previous
//
#include <hip/hip_runtime.h>
#include <hip/hip_bf16.h>
#include <math.h>

#define NN 16384
#define IN_DIM 256
#define HID 128
#define MAXL 128
#define NCLS 64
#define EPS 1e-5f
#define SROW 144  // u16 per S row: 16 data chunks + 2 pad; 72 dw = 8 mod 32

typedef unsigned short u16;
typedef unsigned int u32;
typedef __attribute__((ext_vector_type(8))) short short8;
typedef __attribute__((ext_vector_type(4))) float f32x4;

// scr layout (floats), ALIASED onto S (only used after last read of S data):
// POOLED[128] | RSC[256..]. All scr/csum use is write-before-read flat f32,
// so no pre-zeroing of pads is needed anywhere.
#define POOLED 0
#define RSC 128
#define Z1 384

__device__ __forceinline__ u16 f2bf(float f) {
  union { float f; u32 i; } v; v.f = f;
  u32 x = v.i;
  u32 r = (x + 0x7fffu + ((x >> 16) & 1u)) >> 16;
  return (u16)r;
}
#if __has_builtin(__builtin_amdgcn_cvt_pk_bf16_f32)
typedef __bf16 bf16x2 __attribute__((ext_vector_type(2)));
__device__ __forceinline__ u32 pack2(float a, float b) {
  bf16x2 h = __builtin_amdgcn_cvt_pk_bf16_f32(a, b);
  u32 u;
  __builtin_memcpy(&u, &h, 4);
  return u;
}
#else
__device__ __forceinline__ u32 pack2(float a, float b) {
  return (u32)f2bf(a) | ((u32)f2bf(b) << 16);
}
#endif

__device__ __forceinline__ float fast_exp2(float x) {
#if __has_builtin(__builtin_amdgcn_exp2f)
  return __builtin_amdgcn_exp2f(x);
#else
  return exp2f(x);
#endif
}
__device__ __forceinline__ float fast_rcp(float x) {
#if __has_builtin(__builtin_amdgcn_rcpf)
  return __builtin_amdgcn_rcpf(x);
#else
  return 1.0f / x;
#endif
}
// tanh-form GELU: x * (1 - 1/(1+exp2(x*(A + B*x^2))))
__device__ __forceinline__ float gelu_fast(float x) {
  float s = x * x;
  float p = __builtin_fmaf(s, 0.1029445f, 2.3022038f);
  float e = fast_exp2(x * p);
  float r = fast_rcp(e + 1.0f);
  return x - x * r;
}

// ---- 16-lane (DPP row) butterfly reduction on the VALU pipe
template <int CTRL>
__device__ __forceinline__ float dpp_add(float x) {
  int y = __builtin_amdgcn_update_dpp(0, __builtin_bit_cast(int, x), CTRL,
                                      0xF, 0xF, true);
  return x + __builtin_bit_cast(float, y);
}
__device__ __forceinline__ float row_reduce16(float x) {
  x = dpp_add<0xB1>(x);   // quad_perm [1,0,3,2]  (xor 1)
  x = dpp_add<0x4E>(x);   // quad_perm [2,3,0,1]  (xor 2)
  x = dpp_add<0x124>(x);  // row_ror:4  (cross-quad)
  x = dpp_add<0x128>(x);  // row_ror:8  (cross-half)
  return x;
}

// ---------------- K1: H = LN(GELU(node_feat @ local_W + b)), 8 nodes/block --
__global__ __launch_bounds__(128) void k_local_encoder(
    const float* __restrict__ node_feat, const float* __restrict__ local_W,
    const float* __restrict__ local_b, const float* __restrict__ lnw,
    const float* __restrict__ lnb, u16* __restrict__ H) {
  __shared__ float x[8][IN_DIM];
  __shared__ float red[8][2][2];
  int n0 = blockIdx.x * 8, j = threadIdx.x;
  for (int q = j; q < 8 * IN_DIM; q += 128)
    x[q >> 8][q & 255] = node_feat[n0 * IN_DIM + q];
  __syncthreads();
  float acc[8];
#pragma unroll
  for (int p = 0; p < 8; ++p) acc[p] = local_b[j];
  for (int k = 0; k < IN_DIM; ++k) {
    float w = local_W[k * HID + j];
#pragma unroll
    for (int p = 0; p < 8; ++p) acc[p] += x[p][k] * w;
  }
  float lw = lnw[j], lb = lnb[j];
  int wave = j >> 6;
  float g[8];
#pragma unroll
  for (int p = 0; p < 8; ++p) {
    g[p] = gelu_fast(acc[p]);
    float s = g[p], ss = g[p] * g[p];
#pragma unroll
    for (int o = 1; o < 64; o <<= 1) {
      s += __shfl_xor(s, o, 64);
      ss += __shfl_xor(ss, o, 64);
    }
    if ((j & 63) == 0) { red[p][wave][0] = s; red[p][wave][1] = ss; }
  }
  __syncthreads();
#pragma unroll
  for (int p = 0; p < 8; ++p) {
    float S = red[p][0][0] + red[p][1][0];
    float SS = red[p][0][1] + red[p][1][1];
    float m = S * (1.0f / 128.0f);
    float v = SS * (1.0f / 128.0f) - m * m;
    float y = (g[p] - m) * rsqrtf(v + EPS) * lw + lb;
    H[(n0 + p) * HID + j] = f2bf(y);
  }
}

// ------- K2: repack weights to bf16, A-fragment (wave-coalesced) order -----
// layout in dst: conv [0, CONV_ELEMS) | ssm [.., +HID*HID) | biasrow [.., +HID)
#define CONV_ELEMS (3 * 4 * 3 * 8 * 512)  // 147456
#define PREP_TOTAL (CONV_ELEMS + HID * HID + HID)
__global__ __launch_bounds__(256) void k_prep(
    const float* __restrict__ conv_w, const float* __restrict__ ssm_W,
    const float* __restrict__ ssm_b, u16* __restrict__ dst) {
  int idx = blockIdx.x * 256 + threadIdx.x;
  if (idx >= PREP_TOTAL) return;
  if (idx < CONV_ELEMS) {
    int e = idx & 7, quad = (idx >> 3) & 3, li16 = (idx >> 5) & 15,
        g = (idx >> 9) & 7;
    int rest = idx >> 12;  // 0..35 = ((li*4+kc)*3+tap)
    int tap = rest % 3, kcli = rest / 3;
    int kc = kcli & 3, li = kcli >> 2;
    int co = g * 16 + li16, ci = kc * 32 + quad * 8 + e;
    dst[idx] = f2bf(conv_w[((li * HID + co) * HID + ci) * 3 + tap]);
  } else if (idx < CONV_ELEMS + HID * HID) {
    int r = idx - CONV_ELEMS;
    int e = r & 7, quad = (r >> 3) & 3, li16 = (r >> 5) & 15, g = (r >> 9) & 7;
    int kc = r >> 12;
    dst[idx] = f2bf(ssm_W[(kc * 32 + quad * 8 + e) * HID + g * 16 + li16]);
  } else {
    // bf16 ssm bias row: the exact value padded sequence rows take
    dst[idx] = f2bf(ssm_b[idx - CONV_ELEMS - HID * HID]);
  }
}

// ---------------- GEMM core: D[co][l] = sum_ci,tap W[co][ci] * Sin[l+shift][ci]
// w_frag (A): lane m=li16 -> co, k = quad*8+e  -> coalesced 1KB global chunk
// x_frag (B): lane n=li16 -> l,  k = quad*8+e  -> ds_read_b128 of Sin row
// chunk swizzle: phys = c ^ (row & 7); 16j = 0 mod 8 -> j-invariant
// kc loop ROLLED (unroll 1): at 4 waves/SIMD the TLP hides latency, and the
// smaller prefetch window keeps arch-VGPR demand under the 64 available in
// the forced 128-unified budget (R11 spilled ~3 dwords/thread from the
// fully-unrolled 12-iteration body's hoisted a-loads). FP order unchanged.
template <int TAPS, int DIL>
__device__ __forceinline__ void run_gemm(f32x4 (*acc)[8],
                                         const u16* __restrict__ Wg,
                                         const u16* __restrict__ Sin, int li16,
                                         int quad, int w) {
  const u16* wbase = Wg + w * 1024 + li16 * 32 + quad * 8;
#pragma unroll 1
  for (int kc = 0; kc < 4; ++kc) {
#pragma unroll
    for (int tap = 0; tap < TAPS; ++tap) {
      const int shift = (TAPS == 3) ? (tap - 1) * DIL : 0;
      const u16* wp = wbase + (kc * TAPS + tap) * 4096;
      short8 a0 = *(const short8*)wp;
      short8 a1 = *(const short8*)(wp + 512);
      int base_row = 4 + li16 + shift;
      int phys = (kc * 4 + quad) ^ (base_row & 7);
      const u16* sp = Sin + base_row * SROW + phys * 8;
#pragma unroll
      for (int j0 = 0; j0 < 8; j0 += 2) {
        short8 b[2];
#pragma unroll
        for (int jj = 0; jj < 2; ++jj)
          b[jj] = *(const short8*)(sp + (j0 + jj) * 16 * SROW);
#pragma unroll
        for (int jj = 0; jj < 2; ++jj) {
          acc[0][j0 + jj] = __builtin_amdgcn_mfma_f32_16x16x32_bf16(
              a0, b[jj], acc[0][j0 + jj], 0, 0, 0);
          acc[1][j0 + jj] = __builtin_amdgcn_mfma_f32_16x16x32_bf16(
              a1, b[jj], acc[1][j0 + jj], 0, 0, 0);
        }
      }
    }
  }
}

// init accumulators with per-co bias (uniform over l)
__device__ __forceinline__ void bias_acc(f32x4 (*acc)[8],
                                         const float* __restrict__ cb,
                                         int cobase, int quad) {
#pragma unroll
  for (int i = 0; i < 2; ++i) {
    f32x4 b4 = *(const f32x4*)(cb + cobase + i * 16 + quad * 4);
#pragma unroll
    for (int j = 0; j < 8; ++j) acc[i][j] = b4;
  }
}

// ------------- K_SSM: H2 = H @ ssm_W + ssm_b (once per node, in place) -----
// 128 nodes/block; stages H rows into the same swizzled S layout, one
// run_gemm<1,0>, bf16-pack, store back over H. Bit-identical to the former
// per-gather ssm stage (same mfma order, same f32 bias add, same pack).
__global__ __launch_bounds__(256) void k_ssm(const float* __restrict__ ssm_b,
                                             const u16* __restrict__ ssmW3,
                                             u16* __restrict__ H) {
  __shared__ __align__(16) u16 S[136 * SROW];
  int t = threadIdx.x;
  int lane = t & 63, w = t >> 6;
  int li16 = lane & 15, quad = lane >> 4;
  int n0 = blockIdx.x * 128;
  {
    int l = t >> 1, h = t & 1;
    const uint4* Hrow = (const uint4*)(H + (n0 + l) * HID + h * 64);
    int row = 4 + l, rx = row & 7;
#pragma unroll
    for (int mb = 0; mb < 8; ++mb) {
      uint4 v = Hrow[mb];
      int phys = (h * 8 + mb) ^ rx;
      *(uint4*)&S[row * SROW + phys * 8] = v;
    }
  }
  __syncthreads();  // all H reads staged before in-place overwrite
  f32x4 acc[2][8];
  int cobase = w * 32;
  bias_acc(acc, ssm_b, cobase, quad);
  run_gemm<1, 0>(acc, ssmW3, S, li16, quad, w);
  u32* H2 = (u32*)H;
#pragma unroll
  for (int i = 0; i < 2; ++i) {
    int co0 = cobase + i * 16 + quad * 4;
#pragma unroll
    for (int j = 0; j < 8; ++j) {
      int node = n0 + 16 * j + li16;
      uint2 pk;
      pk.x = pack2(acc[i][j][0], acc[i][j][1]);
      pk.y = pack2(acc[i][j][2], acc[i][j][3]);
      *(uint2*)&H2[node * 64 + co0 / 2] = pk;  // 8B-aligned (co0 % 4 == 0)
    }
  }
}

// conv stage IN PLACE on S, WRITE-THROUGH epilogue: gemm -> barrier (all
// reads done) -> gelu/LN and store each packed uint2 AS COMPUTED -> barrier.
// No pk[2][8] register array is ever live: epilogue peak = acc + stats only,
// which is what lets the kernel fit the 128-reg / 4-waves-per-SIMD tier.
template <int DIL>
__device__ __forceinline__ void conv_stage(
    f32x4 (*acc)[8], const u16* __restrict__ Wg, u16* __restrict__ S,
    int li16, int quad, int w, const float* __restrict__ cb,
    const float* __restrict__ gw, const float* __restrict__ gb) {
  int cobase = w * 32;
  bias_acc(acc, cb, cobase, quad);
  run_gemm<3, DIL>(acc, Wg, S, li16, quad, w);
  __syncthreads();  // all waves' reads of S complete; writes may now proceed
#pragma unroll
  for (int i = 0; i < 2; ++i) {
    f32x4 s = (f32x4){0.f, 0.f, 0.f, 0.f}, ss = s;
#pragma unroll
    for (int j = 0; j < 8; ++j) {
#pragma unroll
      for (int r = 0; r < 4; ++r) acc[i][j][r] = gelu_fast(acc[i][j][r]);
      s += acc[i][j];
      ss += acc[i][j] * acc[i][j];
    }
    // reduce over the 16 l-lanes (DPP row ops, VALU pipe — no LDS)
#pragma unroll
    for (int r = 0; r < 4; ++r) {
      s[r] = row_reduce16(s[r]);
      ss[r] = row_reduce16(ss[r]);
    }
    f32x4 inv, im;
#pragma unroll
    for (int r = 0; r < 4; ++r) {
      float m = s[r] * (1.0f / 128.0f);
      float var = ss[r] * (1.0f / 128.0f) - m * m;
      inv[r] = rsqrtf(var + EPS);
      im[r] = m * inv[r];
    }
    int c8 = w * 4 + 2 * i + (quad >> 1);
    // y = fma(fma(acc, inv, -im), gl, bl); packed+stored immediately
#pragma unroll
    for (int j = 0; j < 8; ++j) {
      int l = 16 * j + li16;
      float gl = gw[l], bl = gb[l];  // streamed from L1, not reg-resident
      float y0 = __builtin_fmaf(__builtin_fmaf(acc[i][j][0], inv[0], -im[0]), gl, bl);
      float y1 = __builtin_fmaf(__builtin_fmaf(acc[i][j][1], inv[1], -im[1]), gl, bl);
      float y2 = __builtin_fmaf(__builtin_fmaf(acc[i][j][2], inv[2], -im[2]), gl, bl);
      float y3 = __builtin_fmaf(__builtin_fmaf(acc[i][j][3], inv[3], -im[3]), gl, bl);
      uint2 pk;
      pk.x = pack2(y0, y1);
      pk.y = pack2(y2, y3);
      int row = 4 + 16 * j + li16;
      int phys = c8 ^ (row & 7);
      *(uint2*)&S[row * SROW + phys * 8 + (quad & 1) * 4] = pk;
    }
  }
  __syncthreads();  // S writes visible before next stage reads
}

// FINAL conv stage with FUSED masked pooling: conv3's output is only pooled,
// so never pack/store it. Masked LN coefficients (0 for padded l) make y
// exactly 0 for invalid positions via fma(q,0,0); pool-sum runs in registers
// + DPP row-reduce; each csum[co] has exactly ONE writer (li16==0 lane) ->
// plain f32x4 stores, no atomics, no pre-zeroing. csum aliases guard rows
// the GEMM reads as halo, so its write must wait for the reads-done barrier.
template <int DIL>
__device__ __forceinline__ void conv_stage_pool(
    f32x4 (*acc)[8], const u16* __restrict__ Wg, u16* __restrict__ S,
    int li16, int quad, int w, const float* __restrict__ cb,
    const float* __restrict__ gw, const float* __restrict__ gb, int len,
    float* __restrict__ csum) {
  int cobase = w * 32;
  bias_acc(acc, cb, cobase, quad);
  run_gemm<3, DIL>(acc, Wg, S, li16, quad, w);
  f32x4 ps[2];
#pragma unroll
  for (int i = 0; i < 2; ++i) {
    f32x4 s = (f32x4){0.f, 0.f, 0.f, 0.f}, ss = s;
#pragma unroll
    for (int j = 0; j < 8; ++j) {
#pragma unroll
      for (int r = 0; r < 4; ++r) acc[i][j][r] = gelu_fast(acc[i][j][r]);
      s += acc[i][j];
      ss += acc[i][j] * acc[i][j];
    }
    // LN stats over ALL 128 l (reference semantics: LN ignores the mask)
#pragma unroll
    for (int r = 0; r < 4; ++r) {
      s[r] = row_reduce16(s[r]);
      ss[r] = row_reduce16(ss[r]);
    }
    f32x4 inv, im;
#pragma unroll
    for (int r = 0; r < 4; ++r) {
      float m = s[r] * (1.0f / 128.0f);
      float var = ss[r] * (1.0f / 128.0f) - m * m;
      inv[r] = rsqrtf(var + EPS);
      im[r] = m * inv[r];
    }
    ps[i] = (f32x4){0.f, 0.f, 0.f, 0.f};
#pragma unroll
    for (int j = 0; j < 8; ++j) {
      int l = 16 * j + li16;
      bool valid = l < len;
      float glm = valid ? gw[l] : 0.f;  // streamed + masked
      float blm = valid ? gb[l] : 0.f;
#pragma unroll
      for (int r = 0; r < 4; ++r)
        ps[i][r] += __builtin_fmaf(
            __builtin_fmaf(acc[i][j][r], inv[r], -im[r]), glm, blm);
    }
#pragma unroll
    for (int r = 0; r < 4; ++r) ps[i][r] = row_reduce16(ps[i][r]);
  }
  __syncthreads();  // all waves' gemm reads of S (incl. guard rows) complete
  if (li16 == 0) {
#pragma unroll
    for (int i = 0; i < 2; ++i)
      *(f32x4*)&csum[cobase + 16 * i + quad * 4] = ps[i];
  }
  __syncthreads();  // csum visible for the matvec
}

__global__ __launch_bounds__(256, 4) void k_main(
    const int* __restrict__ nidx, const int* __restrict__ nlen,
    const u16* __restrict__ Hg, const u16* __restrict__ biasrow,
    const u16* __restrict__ convW3, const float* __restrict__ conv_b,
    const float* __restrict__ lnw, const float* __restrict__ lnb,
    const float* __restrict__ out_W, const float* __restrict__ out_b,
    const float* __restrict__ W1, const float* __restrict__ b1,
    const float* __restrict__ W2, const float* __restrict__ b2,
    float* __restrict__ out) {
  // SINGLE buffer: 136*144*2 = 39168 B.  scr (classifier scratch) aliases S
  // data rows; csum lives in guard rows 132..133 and is written (not
  // accumulated) only after conv3's reads, so no zeroing/atomics needed.
  __shared__ __align__(16) u16 S[136 * SROW];
  float* scr = (float*)S;
  float* csum = (float*)&S[132 * SROW];  // 128 floats

  int n = blockIdx.x, t = threadIdx.x;
  int lane = t & 63, w = t >> 6;
  int li16 = lane & 15, quad = lane >> 4;
  int len = nlen[n];

  // zero guard rows: 16 data chunks per row (8 rows x 16 chunks = 128 uint4);
  // GEMMs read these as the zero-padding halo for the dilated convs
  if (t < 128) {
    int rg = t >> 4, c = t & 15;
    int row = (rg < 4) ? rg : 128 + rg;  // rows 0..3, 132..135
    uint4 z; z.x = 0; z.y = 0; z.z = 0; z.w = 0;
    *(uint4*)&S[row * SROW + c * 8] = z;
  }
  // gather: S row (4+l) = H2[nidx[l]] (ssm output, hoisted) or bias row
  {
    int l = t >> 1, h = t & 1;
    int nb = nidx[n * MAXL + l];
    bool valid = l < len;
    const uint4* src = valid ? (const uint4*)(Hg + nb * HID + h * 64)
                             : (const uint4*)(biasrow + h * 64);
    int row = 4 + l, rx = row & 7;
#pragma unroll
    for (int mb = 0; mb < 8; ++mb) {
      uint4 v = src[mb];
      int phys = (h * 8 + mb) ^ rx;
      *(uint4*)&S[row * SROW + phys * 8] = v;
    }
  }
  __syncthreads();

  f32x4 acc[2][8];

  // ---- 3 dilated conv layers in place on S; conv3 fuses the masked pool
  conv_stage<1>(acc, convW3, S, li16, quad, w, conv_b, lnw, lnb);
  conv_stage<2>(acc, convW3 + 49152, S, li16, quad, w, conv_b + HID,
                lnw + HID, lnb + HID);
  conv_stage_pool<4>(acc, convW3 + 98304, S, li16, quad, w, conv_b + 2 * HID,
                     lnw + 2 * HID, lnb + 2 * HID, len, csum);

  // ---- project pooled sum: pooled = (csum @ out_W)/len + out_b
  // (identical algebra to pooling after projection; f32 order differs only)
  {
    int co = t & 127, part = t >> 7;
    const float* wcol = out_W + co;
    float a = 0.f;
    int ci0 = part * 64;
#pragma unroll 8
    for (int ci = ci0; ci < ci0 + 64; ++ci)
      a = __builtin_fmaf(csum[ci], wcol[ci * HID], a);
    scr[RSC + part * 128 + co] = a;
  }
  __syncthreads();
  if (t < 128) {
    float denom = (len > 0) ? (float)len : 1.0f;
    float p = (scr[RSC + t] + scr[RSC + 128 + t]) / denom;
    scr[POOLED + t] = (len > 0) ? (p + out_b[t]) : 0.f;
  }
  __syncthreads();
  // ---- classifier (4 partials; partial layout part*64+j is conflict-free)
  {
    int part = t >> 6, j = t & 63;
    float s = 0.f;
    int c0 = part * 32;
#pragma unroll 8
    for (int c = c0; c < c0 + 32; ++c) s += scr[POOLED + c] * W1[c * 64 + j];
    scr[RSC + part * 64 + j] = s;
  }
  __syncthreads();
  if (t < 64) {
    float z = b1[t] + scr[RSC + t] + scr[RSC + 64 + t] + scr[RSC + 128 + t] +
              scr[RSC + 192 + t];
    scr[Z1 + t] = gelu_fast(z);
  }
  __syncthreads();
  {
    int part = t >> 6, j = t & 63;
    float s = 0.f;
    int c0 = part * 16;
#pragma unroll 8
    for (int c = c0; c < c0 + 16; ++c) s += scr[Z1 + c] * W2[c * 64 + j];
    scr[RSC + part * 64 + j] = s;
  }
  __syncthreads();
  if (t < 64) {
    out[n * NCLS + t] = b2[t] + scr[RSC + t] + scr[RSC + 64 + t] +
                        scr[RSC + 128 + t] + scr[RSC + 192 + t];
  }
}

extern "C" void kernel_launch(void* const* d_in, const int* in_sizes, int n_in,
                              void* d_out, int out_size, void* d_ws,
                              size_t ws_size, hipStream_t stream) {
  const float* node_feat = (const float*)d_in[0];
  const int* nidx = (const int*)d_in[1];
  const int* nlen = (const int*)d_in[2];
  const float* local_W = (const float*)d_in[3];
  const float* local_b = (const float*)d_in[4];
  const float* local_ln_w = (const float*)d_in[5];
  const float* local_ln_b = (const float*)d_in[6];
  const float* ssm_W = (const float*)d_in[7];
  const float* ssm_b = (const float*)d_in[8];
  const float* conv_w = (const float*)d_in[9];
  const float* conv_b = (const float*)d_in[10];
  const float* lnw = (const float*)d_in[11];
  const float* lnb = (const float*)d_in[12];
  const float* outW = (const float*)d_in[13];
  const float* outb = (const float*)d_in[14];
  const float* W1 = (const float*)d_in[15];
  const float* b1 = (const float*)d_in[16];
  const float* W2 = (const float*)d_in[17];
  const float* b2 = (const float*)d_in[18];

  u16* Hws = (u16*)d_ws;                // 16384*128 bf16 (H, then H2 in place)
  u16* convW3 = Hws + NN * HID;         // 147456
  u16* ssmW3 = convW3 + CONV_ELEMS;     // 16384
  u16* biasrow = ssmW3 + HID * HID;     // 128

  k_local_encoder<<<NN / 8, 128, 0, stream>>>(node_feat, local_W, local_b,
                                              local_ln_w, local_ln_b, Hws);
  k_prep<<<(PREP_TOTAL + 255) / 256, 256, 0, stream>>>(conv_w, ssm_W, ssm_b,
                                                       convW3);
  k_ssm<<<NN / 128, 256, 0, stream>>>(ssm_b, ssmW3, Hws);
  k_main<<<NN, 256, 0, stream>>>(nidx, nlen, Hws, biasrow, convW3, conv_b,
                                 lnw, lnb, outW, outb, W1, b1, W2, b2,
                                 (float*)d_out);
}